// Round 7
// baseline (200.043 us; speedup 1.0000x reference)
//
#include <hip/hip_runtime.h>

// PINN fused: u, du/dx0, d2u/dx0^2 of tanh-MLP (2->256->256->256->1), fp32 in/out.
// Round 7: barrier-free wave pipeline + 32x32x16 MFMA.
//   - wave w owns units [32w,32w+32) in all layers (A=W^T strips, D rows=units)
//   - double-buffered LDS activations (buf1: L1->L2, buf2: L2->L3): no anti-deps
//   - per-slab produced-flags (LDS release/acquire); k-loops rotated to start at
//     own slab -> epilogue VALU of one wave overlaps MFMA of others; zero
//     __syncthreads between L1 and the final psum reduce
//   - v_mfma_f32_32x32x16_f16: 1015 vs 845 FLOP/cyc/SIMD, half the instructions
//   - weights prefetched one slab-pair ahead of each acquire spin

#define HID 256
#define TM  32
#define LDK 264   // padded LDS row stride in f16 elems (row stride 528B -> conflict-free frags)

typedef _Float16 half8 __attribute__((ext_vector_type(8)));
typedef _Float16 half4 __attribute__((ext_vector_type(4)));
typedef float    f32x4  __attribute__((ext_vector_type(4)));
typedef float    f32x16 __attribute__((ext_vector_type(16)));

__device__ __forceinline__ float fast_tanh(float z) {
    const float e = __expf(2.0f * z);
#if __has_builtin(__builtin_amdgcn_rcpf)
    const float r = __builtin_amdgcn_rcpf(e + 1.0f);
#else
    const float r = 1.0f / (e + 1.0f);
#endif
    return fmaf(-2.0f, r, 1.0f);
}

__device__ __forceinline__ void wait_flag(int* f) {
    while (__hip_atomic_load(f, __ATOMIC_ACQUIRE, __HIP_MEMORY_SCOPE_WORKGROUP) == 0)
        __builtin_amdgcn_s_sleep(1);
}
__device__ __forceinline__ void set_flag(int* f) {
    __hip_atomic_store(f, 1, __ATOMIC_RELEASE, __HIP_MEMORY_SCOPE_WORKGROUP);
}

// Pack W2/W3 (fp32 [256][256], row=k, col=n) into 32x32x16 A-fragment order for
// W^T, fp16 hi only. A[m][k]: m = strip*32 + (lane&31), k = c*16 + (lane>>5)*8 + j.
// ws layout (f16 elems): W2 @ 0, W3 @ 65536.  storage idx = ((s*16+c)*64+lane)*8+j.
__global__ __launch_bounds__(256) void prep_w(const float* __restrict__ W2,
                                              const float* __restrict__ W3,
                                              _Float16* __restrict__ wsf) {
    const int t = blockIdx.x * 256 + threadIdx.x;     // 0..16383
    const float* __restrict__ W = (t >> 13) ? W3 : W2;
    _Float16* dst = wsf + (size_t)(t >> 13) * 65536;
    const int r    = t & 8191;
    const int s    = r >> 10;          // strip 0..7
    const int c    = (r >> 6) & 15;    // k-chunk 0..15
    const int lane = r & 63;
    const int row0 = c * 16 + ((lane >> 5) << 3);     // k
    const int col  = s * 32 + (lane & 31);            // unit (m)
    half8 vh;
    #pragma unroll
    for (int j = 0; j < 8; ++j)
        vh[j] = (_Float16)W[(size_t)(row0 + j) * HID + col];
    *(half8*)&dst[(size_t)r * 8] = vh;
}

__global__ __launch_bounds__(512) void pinn_mfma(
    const float* __restrict__ x,
    const float* __restrict__ W1, const float* __restrict__ b1,
    const float* __restrict__ b2, const float* __restrict__ b3,
    const float* __restrict__ W4, const float* __restrict__ b4,
    const _Float16* __restrict__ wsf,
    float* __restrict__ out, int B)
{
    __shared__ __align__(16) _Float16 buf1[3][TM][LDK];
    __shared__ __align__(16) _Float16 buf2[3][TM][LDK];
    __shared__ float psum[8][3][TM];
    __shared__ int flag1[8];
    __shared__ int flag2[8];

    const int tid  = threadIdx.x;
    const int s0   = blockIdx.x * TM;
    const int lane = tid & 63;
    const int wave = tid >> 6;          // 0..7 = unit strip
    const int n    = lane & 31;         // sample within tile / frag col
    const int q    = lane >> 5;         // k half / unit sub-strip
    const int q8   = q * 8;

    if (tid < 8) { flag1[tid] = 0; flag2[tid] = 0; }
    __syncthreads();                    // flags visible before anyone spins

    // ---------- Layer 1: wave w produces slab w (units 32w..32w+31, all samples) ----------
    {
        const int u0 = wave * 32 + q * 16;            // 16 units for this lane
        const float x0 = x[(s0 + n) * 2 + 0];
        const float x1 = x[(s0 + n) * 2 + 1];
        #pragma unroll
        for (int g = 0; g < 4; ++g) {
            const f32x4 wa = *(const f32x4*)&W1[u0 + g * 4];          // W1[0][u] = z1'
            const f32x4 wb = *(const f32x4*)&W1[HID + u0 + g * 4];
            const f32x4 bv = *(const f32x4*)&b1[u0 + g * 4];
            half4 h0, h1, h2;
            #pragma unroll
            for (int r = 0; r < 4; ++r) {
                const float z  = fmaf(x0, wa[r], fmaf(x1, wb[r], bv[r]));
                const float a  = fast_tanh(z);
                const float sN = 1.0f - a * a;
                const float ad  = sN * wa[r];
                const float add = -2.0f * a * ad * wa[r];
                h0[r] = (_Float16)a;
                h1[r] = (_Float16)ad;
                h2[r] = (_Float16)add;
            }
            *(half4*)&buf1[0][n][u0 + g * 4] = h0;
            *(half4*)&buf1[1][n][u0 + g * 4] = h1;
            *(half4*)&buf1[2][n][u0 + g * 4] = h2;
        }
    }
    if (lane == 0) set_flag(&flag1[wave]);

    f32x16 acc0, acc1, acc2;

    // ---------- Layer 2 k-loop: rotated slab order, acquire flags1 ----------
    {
        const _Float16* __restrict__ Wp = wsf;        // W2 pack
        #pragma unroll
        for (int e = 0; e < 16; ++e) { acc0[e] = 0.f; acc1[e] = 0.f; acc2[e] = 0.f; }

        #define WIDX(c) (((size_t)(wave * 16 + (c)) * 64 + lane) * 8)
        half8 wA = *(const half8*)&Wp[WIDX(2 * wave)];
        half8 wB = *(const half8*)&Wp[WIDX(2 * wave + 1)];
        #pragma unroll
        for (int i = 0; i < 8; ++i) {
            const int p = (wave + i) & 7;
            half8 wAn, wBn;
            if (i < 7) {
                const int pn = (wave + i + 1) & 7;
                wAn = *(const half8*)&Wp[WIDX(2 * pn)];
                wBn = *(const half8*)&Wp[WIDX(2 * pn + 1)];
            }
            if (i) wait_flag(&flag1[p]);
            {
                const int cc = 2 * p;
                const half8 b0 = *(const half8*)&buf1[0][n][cc * 16 + q8];
                const half8 b1f = *(const half8*)&buf1[1][n][cc * 16 + q8];
                const half8 b2f = *(const half8*)&buf1[2][n][cc * 16 + q8];
                acc0 = __builtin_amdgcn_mfma_f32_32x32x16_f16(wA, b0,  acc0, 0, 0, 0);
                acc1 = __builtin_amdgcn_mfma_f32_32x32x16_f16(wA, b1f, acc1, 0, 0, 0);
                acc2 = __builtin_amdgcn_mfma_f32_32x32x16_f16(wA, b2f, acc2, 0, 0, 0);
            }
            {
                const int cc = 2 * p + 1;
                const half8 b0 = *(const half8*)&buf1[0][n][cc * 16 + q8];
                const half8 b1f = *(const half8*)&buf1[1][n][cc * 16 + q8];
                const half8 b2f = *(const half8*)&buf1[2][n][cc * 16 + q8];
                acc0 = __builtin_amdgcn_mfma_f32_32x32x16_f16(wB, b0,  acc0, 0, 0, 0);
                acc1 = __builtin_amdgcn_mfma_f32_32x32x16_f16(wB, b1f, acc1, 0, 0, 0);
                acc2 = __builtin_amdgcn_mfma_f32_32x32x16_f16(wB, b2f, acc2, 0, 0, 0);
            }
            wA = wAn; wB = wBn;
        }
    }

    // ---------- Layer 2 epilogue: D(row=unit,col=sample) -> buf2 slab `wave` ----------
    // D: col = lane&31 = sample, row = (reg&3) + 8*(reg>>2) + 4*q  (+ wave*32)
    #pragma unroll
    for (int g = 0; g < 4; ++g) {
        const int ub = wave * 32 + g * 8 + q * 4;     // 4 consecutive units
        const f32x4 bb = *(const f32x4*)&b2[ub];
        half4 h0, h1, h2;
        #pragma unroll
        for (int r = 0; r < 4; ++r) {
            const float z   = acc0[g * 4 + r] + bb[r];
            const float a   = fast_tanh(z);
            const float sN  = 1.0f - a * a;
            const float zd  = acc1[g * 4 + r];
            const float zdd = acc2[g * 4 + r];
            const float ad  = sN * zd;
            const float add = fmaf(sN, zdd, -2.0f * a * ad * zd);
            h0[r] = (_Float16)a;
            h1[r] = (_Float16)ad;
            h2[r] = (_Float16)add;
        }
        *(half4*)&buf2[0][n][ub] = h0;
        *(half4*)&buf2[1][n][ub] = h1;
        *(half4*)&buf2[2][n][ub] = h2;
    }
    if (lane == 0) set_flag(&flag2[wave]);

    // ---------- Layer 3 k-loop: rotated, acquire flags2 ----------
    {
        const _Float16* __restrict__ Wp = wsf + 65536;   // W3 pack
        #pragma unroll
        for (int e = 0; e < 16; ++e) { acc0[e] = 0.f; acc1[e] = 0.f; acc2[e] = 0.f; }

        half8 wA = *(const half8*)&Wp[WIDX(2 * wave)];
        half8 wB = *(const half8*)&Wp[WIDX(2 * wave + 1)];
        #pragma unroll
        for (int i = 0; i < 8; ++i) {
            const int p = (wave + i) & 7;
            half8 wAn, wBn;
            if (i < 7) {
                const int pn = (wave + i + 1) & 7;
                wAn = *(const half8*)&Wp[WIDX(2 * pn)];
                wBn = *(const half8*)&Wp[WIDX(2 * pn + 1)];
            }
            if (i) wait_flag(&flag2[p]);
            {
                const int cc = 2 * p;
                const half8 b0 = *(const half8*)&buf2[0][n][cc * 16 + q8];
                const half8 b1f = *(const half8*)&buf2[1][n][cc * 16 + q8];
                const half8 b2f = *(const half8*)&buf2[2][n][cc * 16 + q8];
                acc0 = __builtin_amdgcn_mfma_f32_32x32x16_f16(wA, b0,  acc0, 0, 0, 0);
                acc1 = __builtin_amdgcn_mfma_f32_32x32x16_f16(wA, b1f, acc1, 0, 0, 0);
                acc2 = __builtin_amdgcn_mfma_f32_32x32x16_f16(wA, b2f, acc2, 0, 0, 0);
            }
            {
                const int cc = 2 * p + 1;
                const half8 b0 = *(const half8*)&buf2[0][n][cc * 16 + q8];
                const half8 b1f = *(const half8*)&buf2[1][n][cc * 16 + q8];
                const half8 b2f = *(const half8*)&buf2[2][n][cc * 16 + q8];
                acc0 = __builtin_amdgcn_mfma_f32_32x32x16_f16(wB, b0,  acc0, 0, 0, 0);
                acc1 = __builtin_amdgcn_mfma_f32_32x32x16_f16(wB, b1f, acc1, 0, 0, 0);
                acc2 = __builtin_amdgcn_mfma_f32_32x32x16_f16(wB, b2f, acc2, 0, 0, 0);
            }
            wA = wAn; wB = wBn;
        }
        #undef WIDX
    }

    // ---------- Layer 3 epilogue fused with W4 dot (registers only) ----------
    {
        float pd0 = 0.f, pd1 = 0.f, pd2 = 0.f;
        #pragma unroll
        for (int g = 0; g < 4; ++g) {
            const int ub = wave * 32 + g * 8 + q * 4;
            const f32x4 bb = *(const f32x4*)&b3[ub];
            const f32x4 w4 = *(const f32x4*)&W4[ub];
            #pragma unroll
            for (int r = 0; r < 4; ++r) {
                const float z   = acc0[g * 4 + r] + bb[r];
                const float a   = fast_tanh(z);
                const float sN  = 1.0f - a * a;
                const float zd  = acc1[g * 4 + r];
                const float zdd = acc2[g * 4 + r];
                const float ad  = sN * zd;
                const float add = fmaf(sN, zdd, -2.0f * a * ad * zd);
                pd0 = fmaf(a,   w4[r], pd0);
                pd1 = fmaf(ad,  w4[r], pd1);
                pd2 = fmaf(add, w4[r], pd2);
            }
        }
        // lanes n and n+32 hold the two halves of each sample's strip-partial
        pd0 += __shfl_xor(pd0, 32, 64);
        pd1 += __shfl_xor(pd1, 32, 64);
        pd2 += __shfl_xor(pd2, 32, 64);
        if (lane < 32) {
            psum[wave][0][lane] = pd0;
            psum[wave][1][lane] = pd1;
            psum[wave][2][lane] = pd2;
        }
    }
    __syncthreads();

    if (tid < 96) {
        const int s = tid >> 5;          // 0:u 1:du 2:d2u
        const int m = tid & 31;
        float v = 0.f;
        #pragma unroll
        for (int w = 0; w < 8; ++w) v += psum[w][s][m];
        if (s == 0) v += b4[0];
        out[(size_t)s * B + s0 + m] = v;
    }
}

extern "C" void kernel_launch(void* const* d_in, const int* in_sizes, int n_in,
                              void* d_out, int out_size, void* d_ws, size_t ws_size,
                              hipStream_t stream) {
    const float* x  = (const float*)d_in[0];
    const float* W1 = (const float*)d_in[1];
    const float* b1 = (const float*)d_in[2];
    const float* W2 = (const float*)d_in[3];
    const float* b2 = (const float*)d_in[4];
    const float* W3 = (const float*)d_in[5];
    const float* b3 = (const float*)d_in[6];
    const float* W4 = (const float*)d_in[7];
    const float* b4 = (const float*)d_in[8];
    float* out = (float*)d_out;

    const int B = in_sizes[0] / 2;      // x is (B, 2)

    prep_w<<<64, 256, 0, stream>>>(W2, W3, (_Float16*)d_ws);
    pinn_mfma<<<B / TM, 512, 0, stream>>>(x, W1, b1, b2, b3, W4, b4,
                                          (const _Float16*)d_ws, out, B);
}

// Round 8
// 196.021 us; speedup vs baseline: 1.0205x; 1.0205x over previous
//
#include <hip/hip_runtime.h>

// PINN fused: u, du/dx0, d2u/dx0^2 of tanh-MLP (2->256->256->256->1), fp32 in/out.
// Round 8: round-7 layout (wave-owned 32-unit strips, 32x32x16 MFMA, fused W4
// epilogue) but BARRIERED with a single in-place activation buffer:
//   LDS 105KB -> 50.7KB  =>  3 blocks/CU, 24 waves/CU. Cross-block overlap
//   (m114 MFMA/VALU co-scheduling) replaces round-7's failed intra-block
//   pipeline (1 block/CU, phase-locked waves).
//   psum is aliased into the activation buffer (dead after last k-loop read).

#define HID 256
#define TM  32
#define LDK 264   // padded LDS row stride in f16 (528B -> 2-way-max bank aliasing, free)

typedef _Float16 half8 __attribute__((ext_vector_type(8)));
typedef _Float16 half4 __attribute__((ext_vector_type(4)));
typedef float    f32x4  __attribute__((ext_vector_type(4)));
typedef float    f32x16 __attribute__((ext_vector_type(16)));

__device__ __forceinline__ float fast_tanh(float z) {
    const float e = __expf(2.0f * z);
#if __has_builtin(__builtin_amdgcn_rcpf)
    const float r = __builtin_amdgcn_rcpf(e + 1.0f);
#else
    const float r = 1.0f / (e + 1.0f);
#endif
    return fmaf(-2.0f, r, 1.0f);
}

// Pack W2/W3 (fp32 [256][256], row=k, col=n) into 32x32x16 A-fragment order for
// W^T, fp16. A[m][k]: m = strip*32 + (lane&31), k = c*16 + (lane>>5)*8 + j.
// ws layout (f16 elems): W2 @ 0, W3 @ 65536.  storage idx = ((s*16+c)*64+lane)*8+j.
__global__ __launch_bounds__(256) void prep_w(const float* __restrict__ W2,
                                              const float* __restrict__ W3,
                                              _Float16* __restrict__ wsf) {
    const int t = blockIdx.x * 256 + threadIdx.x;     // 0..16383
    const float* __restrict__ W = (t >> 13) ? W3 : W2;
    _Float16* dst = wsf + (size_t)(t >> 13) * 65536;
    const int r    = t & 8191;
    const int s    = r >> 10;          // strip 0..7
    const int c    = (r >> 6) & 15;    // k-chunk 0..15
    const int lane = r & 63;
    const int row0 = c * 16 + ((lane >> 5) << 3);     // k
    const int col  = s * 32 + (lane & 31);            // unit (m)
    half8 vh;
    #pragma unroll
    for (int j = 0; j < 8; ++j)
        vh[j] = (_Float16)W[(size_t)(row0 + j) * HID + col];
    *(half8*)&dst[(size_t)r * 8] = vh;
}

__global__ __launch_bounds__(512) void pinn_mfma(
    const float* __restrict__ x,
    const float* __restrict__ W1, const float* __restrict__ b1,
    const float* __restrict__ b2, const float* __restrict__ b3,
    const float* __restrict__ W4, const float* __restrict__ b4,
    const _Float16* __restrict__ wsf,
    float* __restrict__ out, int B)
{
    __shared__ __align__(16) _Float16 buf[3][TM][LDK];   // 50,688 B total
    float* const psum = (float*)&buf[0][0][0];           // aliased: [w][s][m] = w*96+s*32+m

    const int tid  = threadIdx.x;
    const int s0   = blockIdx.x * TM;
    const int lane = tid & 63;
    const int wave = tid >> 6;          // 0..7 = unit strip
    const int n    = lane & 31;         // sample within tile / frag col
    const int q    = lane >> 5;         // k half / unit sub-strip
    const int q8   = q * 8;

    // ---------- Layer 1: wave w produces strip w (units 32w..32w+31, all samples) ----------
    {
        const int u0 = wave * 32 + q * 16;            // 16 units for this lane
        const float2 xv = *(const float2*)&x[(size_t)(s0 + n) * 2];
        #pragma unroll
        for (int g = 0; g < 4; ++g) {
            const f32x4 wa = *(const f32x4*)&W1[u0 + g * 4];          // W1[0][u] = z1'
            const f32x4 wb = *(const f32x4*)&W1[HID + u0 + g * 4];
            const f32x4 bv = *(const f32x4*)&b1[u0 + g * 4];
            half4 h0, h1, h2;
            #pragma unroll
            for (int r = 0; r < 4; ++r) {
                const float z  = fmaf(xv.x, wa[r], fmaf(xv.y, wb[r], bv[r]));
                const float a  = fast_tanh(z);
                const float sN = 1.0f - a * a;
                const float ad  = sN * wa[r];
                const float add = -2.0f * a * ad * wa[r];
                h0[r] = (_Float16)a;
                h1[r] = (_Float16)ad;
                h2[r] = (_Float16)add;
            }
            *(half4*)&buf[0][n][u0 + g * 4] = h0;
            *(half4*)&buf[1][n][u0 + g * 4] = h1;
            *(half4*)&buf[2][n][u0 + g * 4] = h2;
        }
    }
    __syncthreads();

    f32x16 acc0, acc1, acc2;
    #define WIDX(c) (((size_t)(wave * 16 + (c)) * 64 + lane) * 8)

    // ---------- Layer 2 k-loop ----------
    {
        const _Float16* __restrict__ Wp = wsf;        // W2 pack
        #pragma unroll
        for (int e = 0; e < 16; ++e) { acc0[e] = 0.f; acc1[e] = 0.f; acc2[e] = 0.f; }

        half8 wcur = *(const half8*)&Wp[WIDX(0)];
        #pragma unroll 4
        for (int c = 0; c < 16; ++c) {
            half8 wnext;
            if (c < 15) wnext = *(const half8*)&Wp[WIDX(c + 1)];
            const half8 b0 = *(const half8*)&buf[0][n][c * 16 + q8];
            const half8 b1f = *(const half8*)&buf[1][n][c * 16 + q8];
            const half8 b2f = *(const half8*)&buf[2][n][c * 16 + q8];
            acc0 = __builtin_amdgcn_mfma_f32_32x32x16_f16(wcur, b0,  acc0, 0, 0, 0);
            acc1 = __builtin_amdgcn_mfma_f32_32x32x16_f16(wcur, b1f, acc1, 0, 0, 0);
            acc2 = __builtin_amdgcn_mfma_f32_32x32x16_f16(wcur, b2f, acc2, 0, 0, 0);
            wcur = wnext;
        }
    }
    __syncthreads();     // all waves done reading buf before in-place overwrite

    // ---------- Layer 2 epilogue: D(row=unit,col=sample) -> buf strip `wave` ----------
    // D: col = lane&31 = sample, row = (reg&3) + 8*(reg>>2) + 4*q  (+ wave*32)
    #pragma unroll
    for (int g = 0; g < 4; ++g) {
        const int ub = wave * 32 + g * 8 + q * 4;     // 4 consecutive units
        const f32x4 bb = *(const f32x4*)&b2[ub];
        half4 h0, h1, h2;
        #pragma unroll
        for (int r = 0; r < 4; ++r) {
            const float z   = acc0[g * 4 + r] + bb[r];
            const float a   = fast_tanh(z);
            const float sN  = 1.0f - a * a;
            const float zd  = acc1[g * 4 + r];
            const float zdd = acc2[g * 4 + r];
            const float ad  = sN * zd;
            const float add = fmaf(sN, zdd, -2.0f * a * ad * zd);
            h0[r] = (_Float16)a;
            h1[r] = (_Float16)ad;
            h2[r] = (_Float16)add;
        }
        *(half4*)&buf[0][n][ub] = h0;
        *(half4*)&buf[1][n][ub] = h1;
        *(half4*)&buf[2][n][ub] = h2;
    }
    __syncthreads();

    // ---------- Layer 3 k-loop ----------
    {
        const _Float16* __restrict__ Wp = wsf + 65536;   // W3 pack
        #pragma unroll
        for (int e = 0; e < 16; ++e) { acc0[e] = 0.f; acc1[e] = 0.f; acc2[e] = 0.f; }

        half8 wcur = *(const half8*)&Wp[WIDX(0)];
        #pragma unroll 4
        for (int c = 0; c < 16; ++c) {
            half8 wnext;
            if (c < 15) wnext = *(const half8*)&Wp[WIDX(c + 1)];
            const half8 b0 = *(const half8*)&buf[0][n][c * 16 + q8];
            const half8 b1f = *(const half8*)&buf[1][n][c * 16 + q8];
            const half8 b2f = *(const half8*)&buf[2][n][c * 16 + q8];
            acc0 = __builtin_amdgcn_mfma_f32_32x32x16_f16(wcur, b0,  acc0, 0, 0, 0);
            acc1 = __builtin_amdgcn_mfma_f32_32x32x16_f16(wcur, b1f, acc1, 0, 0, 0);
            acc2 = __builtin_amdgcn_mfma_f32_32x32x16_f16(wcur, b2f, acc2, 0, 0, 0);
            wcur = wnext;
        }
    }
    #undef WIDX

    // ---------- Layer 3 epilogue fused with W4 dot (registers only) ----------
    float pd0 = 0.f, pd1 = 0.f, pd2 = 0.f;
    #pragma unroll
    for (int g = 0; g < 4; ++g) {
        const int ub = wave * 32 + g * 8 + q * 4;
        const f32x4 bb = *(const f32x4*)&b3[ub];
        const f32x4 w4 = *(const f32x4*)&W4[ub];
        #pragma unroll
        for (int r = 0; r < 4; ++r) {
            const float z   = acc0[g * 4 + r] + bb[r];
            const float a   = fast_tanh(z);
            const float sN  = 1.0f - a * a;
            const float zd  = acc1[g * 4 + r];
            const float zdd = acc2[g * 4 + r];
            const float ad  = sN * zd;
            const float add = fmaf(sN, zdd, -2.0f * a * ad * zd);
            pd0 = fmaf(a,   w4[r], pd0);
            pd1 = fmaf(ad,  w4[r], pd1);
            pd2 = fmaf(add, w4[r], pd2);
        }
    }
    // lanes n and n+32 hold the two halves of each sample's strip-partial
    pd0 += __shfl_xor(pd0, 32, 64);
    pd1 += __shfl_xor(pd1, 32, 64);
    pd2 += __shfl_xor(pd2, 32, 64);

    __syncthreads();     // buf's last k-loop reads done -> psum alias is safe
    if (lane < 32) {
        psum[wave * 96 +      lane] = pd0;
        psum[wave * 96 + 32 + lane] = pd1;
        psum[wave * 96 + 64 + lane] = pd2;
    }
    __syncthreads();

    if (tid < 96) {
        const int s = tid >> 5;          // 0:u 1:du 2:d2u
        const int m = tid & 31;
        float v = 0.f;
        #pragma unroll
        for (int w = 0; w < 8; ++w) v += psum[w * 96 + s * 32 + m];
        if (s == 0) v += b4[0];
        out[(size_t)s * B + s0 + m] = v;
    }
}

extern "C" void kernel_launch(void* const* d_in, const int* in_sizes, int n_in,
                              void* d_out, int out_size, void* d_ws, size_t ws_size,
                              hipStream_t stream) {
    const float* x  = (const float*)d_in[0];
    const float* W1 = (const float*)d_in[1];
    const float* b1 = (const float*)d_in[2];
    const float* W2 = (const float*)d_in[3];
    const float* b2 = (const float*)d_in[4];
    const float* W3 = (const float*)d_in[5];
    const float* b3 = (const float*)d_in[6];
    const float* W4 = (const float*)d_in[7];
    const float* b4 = (const float*)d_in[8];
    float* out = (float*)d_out;

    const int B = in_sizes[0] / 2;      // x is (B, 2)

    prep_w<<<64, 256, 0, stream>>>(W2, W3, (_Float16*)d_ws);
    pinn_mfma<<<B / TM, 512, 0, stream>>>(x, W1, b1, b2, b3, W4, b4,
                                          (const _Float16*)d_ws, out, B);
}